// Round 5
// baseline (17.372 us; speedup 1.0000x reference)
//
#include <hip/hip_runtime.h>

#define N 4096
#define BLOCK 256
#define IBLK 512              // i's per block (2 per lane)
#define JC 64                 // j-chunks
#define JCHUNK (N / JC)       // 64 j's per chunk

typedef float v2f __attribute__((ext_vector_type(2)));

// ---- per-pair body, 2 i's packed per lane ---------------------------------
// j-side reads are wave-uniform -> s_load; arithmetic is packed f32 (VOP3P).
template <bool DIAG>
__device__ __forceinline__ void lj_accum2(const float* __restrict__ qj, int j0,
                                          int ia, int ib,
                                          v2f qx2, v2f qy2, v2f qz2,
                                          v2f& fx2, v2f& fy2, v2f& fz2) {
    const v2f C24  = {24.0f, 24.0f};
    const v2f Cm48 = {-48.0f, -48.0f};
    #pragma unroll 8
    for (int jj = 0; jj < JCHUNK; ++jj) {
        const float jx = qj[jj*3+0];     // uniform -> s_load, splat to halves
        const float jy = qj[jj*3+1];
        const float jz = qj[jj*3+2];
        v2f dx = qx2 - jx;
        v2f dy = qy2 - jy;
        v2f dz = qz2 - jz;
        v2f r2 = __builtin_elementwise_fma(dx, dx,
                 __builtin_elementwise_fma(dy, dy, dz * dz));
        v2f u;
        u.x = __builtin_amdgcn_rcpf(r2.x);           // v_rcp_f32 (trans pipe)
        u.y = __builtin_amdgcn_rcpf(r2.y);
        v2f u2 = u * u;
        v2f u3 = u2 * u;
        v2f u4 = u2 * u2;
        // s = u^4 * (24 - 48 u^3)  ==  24 r^-8 - 48 r^-14
        v2f s = u4 * __builtin_elementwise_fma(Cm48, u3, C24);
        if (DIAG) {
            const int j = j0 + jj;
            s.x = (j == ia) ? 0.0f : s.x;            // per-lane predicated
            s.y = (j == ib) ? 0.0f : s.y;
        }
        fx2 = __builtin_elementwise_fma(s, dx, fx2);
        fy2 = __builtin_elementwise_fma(s, dy, fy2);
        fz2 = __builtin_elementwise_fma(s, dz, fz2);
    }
}

// ---- kernel A: force partials (atomic-free) + dq on by==0 blocks ----------
// ws[(by*3 + c)*N + i] = force component c on particle i from j-chunk by.
__global__ __launch_bounds__(BLOCK)
void lj_partial_kernel(const float* __restrict__ q, const float* __restrict__ p,
                       const float* __restrict__ m, float* __restrict__ out,
                       float* __restrict__ ws) {
    const int bx = blockIdx.x;           // i-block (8), 512 i's each
    const int by = blockIdx.y;           // j-chunk (64)
    const int ia = bx * IBLK + threadIdx.x;
    const int ib = ia + BLOCK;
    const int j0 = by * JCHUNK;
    const float* __restrict__ qj = q + j0 * 3;

    const v2f qx2 = {q[ia*3+0], q[ib*3+0]};
    const v2f qy2 = {q[ia*3+1], q[ib*3+1]};
    const v2f qz2 = {q[ia*3+2], q[ib*3+2]};
    v2f fx2 = {0.f, 0.f}, fy2 = {0.f, 0.f}, fz2 = {0.f, 0.f};

    if ((by >> 3) == bx)                 // chunk intersects this i-range
        lj_accum2<true >(qj, j0, ia, ib, qx2, qy2, qz2, fx2, fy2, fz2);
    else
        lj_accum2<false>(qj, j0, ia, ib, qx2, qy2, qz2, fx2, fy2, fz2);

    float* w = ws + (size_t)by * 3 * N;
    w[0*N + ia] = fx2.x;  w[0*N + ib] = fx2.y;   // coalesced SoA stores
    w[1*N + ia] = fy2.x;  w[1*N + ib] = fy2.y;
    w[2*N + ia] = fz2.x;  w[2*N + ib] = fz2.y;

    if (by == 0) {                       // fold dq = p/m into 8 blocks
        const int base = bx * (IBLK * 3);
        #pragma unroll
        for (int k = 0; k < (IBLK * 3) / BLOCK; ++k) {
            const int t = base + k * BLOCK + threadIdx.x;
            out[t] = p[t] / m[t / 3];
        }
    }
}

// ---- kernel B: pure reduction of partials -> dp ---------------------------
__global__ __launch_bounds__(BLOCK)
void lj_reduce_kernel(const float* __restrict__ ws, float* __restrict__ out) {
    const int u = blockIdx.x * BLOCK + threadIdx.x;   // 0..12287
    const int c = u >> 12;               // 0..2
    const int i = u & (N - 1);           // 0..4095
    float acc = 0.f;
    #pragma unroll 8
    for (int k = 0; k < JC; ++k)
        acc += ws[((size_t)k * 3 + c) * N + i];       // coalesced per k
    out[N*3 + i*3 + c] = acc;
}

extern "C" void kernel_launch(void* const* d_in, const int* in_sizes, int n_in,
                              void* d_out, int out_size, void* d_ws, size_t ws_size,
                              hipStream_t stream) {
    const float* q = (const float*)d_in[0];
    const float* p = (const float*)d_in[1];
    const float* m = (const float*)d_in[2];
    float* out = (float*)d_out;
    float* ws  = (float*)d_ws;

    dim3 gridA(N / IBLK, JC);            // 8 x 64 = 512 blocks
    lj_partial_kernel<<<gridA, BLOCK, 0, stream>>>(q, p, m, out, ws);

    lj_reduce_kernel<<<(N * 3) / BLOCK, BLOCK, 0, stream>>>(ws, out);
}